// Round 7
// baseline (249.098 us; speedup 1.0000x reference)
//
#include <hip/hip_runtime.h>
#include <hip/hip_bf16.h>

// Problem constants (from reference)
#define N_NODES 100000
#define FEAT    256
#define HID     128
#define REL     2
#define BATCH   20000
#define KNEI    10

typedef short  bf16x8 __attribute__((ext_vector_type(8)));
typedef _Float16 half8 __attribute__((ext_vector_type(8)));
typedef float  f32x4  __attribute__((ext_vector_type(4)));

// ---------------- fp16 helpers ----------------
__device__ __forceinline__ unsigned short f2h(float x) {
    union { _Float16 h; unsigned short u; } t; t.h = (_Float16)x; return t.u;
}
__device__ __forceinline__ ushort4 pack4h(float a, float b, float c, float d) {
    ushort4 p; p.x = f2h(a); p.y = f2h(b); p.z = f2h(c); p.w = f2h(d); return p;
}

// ---------------- bf16 helpers (fallback path) ----------------
__device__ __forceinline__ unsigned short f2bf(float x) {
    union { float f; unsigned u; } v; v.f = x;
    unsigned r = v.u + 0x7fffu + ((v.u >> 16) & 1u);
    return (unsigned short)(r >> 16);
}
__device__ __forceinline__ ushort4 pack4(float a, float b, float c, float d) {
    ushort4 p; p.x = f2bf(a); p.y = f2bf(b); p.z = f2bf(c); p.w = f2bf(d); return p;
}

// Swizzled B index for logical (k, n), NT n-tiles per kt row:
//   kt=k>>5, j=k&7, hi=(k>>3)&3, lane=hi*16+(n&15), nt=n>>4
//   dest = ((kt*NT+nt)*64 + lane)*8 + j
__device__ __forceinline__ size_t bswi(int k, int n, int NT) {
    int kt = k >> 5, j = k & 7, hi = (k >> 3) & 3;
    int lane = hi * 16 + (n & 15), nt = n >> 4;
    return ((size_t)(kt * NT + nt) * 64 + lane) * 8 + j;
}

// ===========================================================================
// NEW PATH (needs ~51.5 MB workspace)
//   prep_Bf16 : W_det (512x128) -> B-swizzled fp16 ; W_stc^T -> A-swizzled fp16
//   prep_P2   : weight-stationary GEMM, P[rel][node][128] = F[node] @ W_stc[rel]
//   fused2    : gather self (1KB) + P rows (256B) -> K=512 fp16 GEMM + ReLU
// ===========================================================================

// blocks 0..63: Bsw_det (NT=8).
// blocks 64..95: Aswz — A-operand swizzle of W_stc^T, per rel:
//   Aswz[rel][((kt*8+mt)*64 + lane)*8 + j] = W_stc[rel][kt*32+(lane>>4)*8+j][mt*16+(lane&15)]
//   (A frag layout for mfma 16x16x32: row m = lane&15, k = (lane>>4)*8 + j)
__global__ __launch_bounds__(256) void prep_Bf16(const float* __restrict__ W_stc,
                                                 const float* __restrict__ W_det,
                                                 unsigned short* __restrict__ Bsw_det,
                                                 unsigned short* __restrict__ Aswz) {
    const int blk = blockIdx.x, tid = threadIdx.x;
    if (blk < 64) {
        #pragma unroll
        for (int i = 0; i < 4; ++i) {
            const int idx = blk * 1024 + i * 256 + tid;   // < 65536
            const int k = idx >> 7, n = idx & 127;
            Bsw_det[bswi(k, n, 8)] = f2h(W_det[idx]);
        }
    } else {
        const int gid = (blk - 64) * 256 + tid;           // < 8192 = rel*kt*mt*lane
        const int rel = gid >> 12;
        const int kt  = (gid >> 9) & 7;
        const int mt  = (gid >> 6) & 7;
        const int lane = gid & 63;
        const int q = lane >> 4, l16 = lane & 15;
        unsigned short* dst = Aswz + (size_t)rel * 32768 + ((size_t)(kt * 8 + mt) * 64 + lane) * 8;
        #pragma unroll
        for (int j = 0; j < 8; ++j) {
            dst[j] = f2h(W_stc[(size_t)(rel * FEAT + kt * 32 + q * 8 + j) * HID + mt * 16 + l16]);
        }
    }
}

// prep_P2: weight-stationary. Grid 512 (2 blocks/CU, all resident).
//   block b: rel = b>>8, chunk = b&255. Stage Aswz[rel] (64 KB) in LDS once.
//   Wave w grid-strides tiles t = chunk*4+w, +1024, ... over 6250 16-node
//   tiles. Per tile: 16 fp32 dwordx4 B-loads (features rows, each byte read
//   once), cvt to 8 half8 B-frags, 8kt x 8mt MFMA (A from LDS, linear b128,
//   conflict-free), direct ushort4 stores to P (operand swap makes each
//   lane's 4 acc values h-contiguous: h = mt*16 + q*4 + r, node = l16).
//   Kills round-6 prep_P's 800 MB L2 weight re-read + 2 of 3 syncthreads.
__global__ __launch_bounds__(256, 2) void prep_P2(const float* __restrict__ features,
                                                  const unsigned short* __restrict__ Aswz,
                                                  unsigned short* __restrict__ P) {
    __shared__ __align__(16) unsigned short Asw[32768];   // 64 KB
    const int b = blockIdx.x;
    const int rel = b >> 8, chunk = b & 255;
    const int tid = threadIdx.x, w = tid >> 6, lane = tid & 63;
    const int q = lane >> 4, l16 = lane & 15;

    // stage weights (64 KB) into LDS, coalesced uint4
    {
        const uint4* src = (const uint4*)(Aswz + (size_t)rel * 32768);
        uint4* dst = (uint4*)Asw;
        #pragma unroll
        for (int i = 0; i < 16; ++i) dst[i * 256 + tid] = src[i * 256 + tid];
    }
    __syncthreads();

    unsigned short* Pr = P + (size_t)rel * N_NODES * HID;

    for (int t = chunk * 4 + w; t < 6250; t += 1024) {
        const int node = t * 16 + l16;
        const float* frow = features + (size_t)node * FEAT + q * 8;

        // B frags: lane (q,l16) holds F[node l16][kt*32 + q*8 + j]
        half8 bfrag[8];
        #pragma unroll
        for (int kt = 0; kt < 8; ++kt) {
            float4 lo = *(const float4*)(frow + kt * 32);
            float4 hi = *(const float4*)(frow + kt * 32 + 4);
            half8 h;
            h[0] = (_Float16)lo.x; h[1] = (_Float16)lo.y;
            h[2] = (_Float16)lo.z; h[3] = (_Float16)lo.w;
            h[4] = (_Float16)hi.x; h[5] = (_Float16)hi.y;
            h[6] = (_Float16)hi.z; h[7] = (_Float16)hi.w;
            bfrag[kt] = h;
        }

        f32x4 acc[8] = {{0,0,0,0},{0,0,0,0},{0,0,0,0},{0,0,0,0},
                        {0,0,0,0},{0,0,0,0},{0,0,0,0},{0,0,0,0}};
        #pragma unroll
        for (int kt = 0; kt < 8; ++kt) {
            #pragma unroll
            for (int mt = 0; mt < 8; ++mt) {
                half8 a = *(const half8*)(Asw + ((size_t)(kt * 8 + mt) * 64 + lane) * 8);
                acc[mt] = __builtin_amdgcn_mfma_f32_16x16x32_f16(a, bfrag[kt], acc[mt], 0, 0, 0);
            }
        }

        // C: m = h (row = q*4 + r within mt), n = node (col = l16)
        unsigned short* prow = Pr + (size_t)node * HID + q * 4;
        #pragma unroll
        for (int mt = 0; mt < 8; ++mt)
            *(ushort4*)(prow + mt * 16) = pack4h(acc[mt][0], acc[mt][1], acc[mt][2], acc[mt][3]);
    }
}

// fused2: A row = [self fp16 (256) | meanP0 (128) | meanP1 (128)], K=512.
#define AROW2 520   // 512 + 8 pad (fp16 elems)
__global__ __launch_bounds__(256, 6) void fused2(const int* __restrict__ nodes,
                                                 const int* __restrict__ neigh_idx,
                                                 const float* __restrict__ features,
                                                 const unsigned short* __restrict__ P,
                                                 const unsigned short* __restrict__ Bsw_det,
                                                 float* __restrict__ out) {
    __shared__ __align__(16) unsigned short As[16 * AROW2];  // 16640 B
    __shared__ int idxs[336];

    const int blk = blockIdx.x, tid = threadIdx.x;
    const int w = tid >> 6, lane = tid & 63;
    const int grp = lane >> 4, l16 = lane & 15;
    const float4* F4 = (const float4*)features;
    const float inv = 1.0f / (float)KNEI;

    // Phase 0: stage indices
    if (tid < 16)       idxs[tid] = nodes[blk * 16 + tid];
    else if (tid < 176) idxs[tid] = neigh_idx[blk * 160 + (tid - 16)];
    else                idxs[tid] = neigh_idx[BATCH * KNEI + blk * 160 + (tid - 176)];
    const int t2 = tid + 256;
    if (t2 < 336)       idxs[t2] = neigh_idx[BATCH * KNEI + blk * 160 + (t2 - 176)];
    __syncthreads();

    // Phase 1: self gather (1KB f32) + P-row gather (256B fp16, 4 rows/load)
    #pragma unroll
    for (int e = 0; e < 4; ++e) {
        const int m = w * 4 + e;
        float4 sf = F4[(size_t)idxs[m] * 64 + lane];
        *(ushort4*)(As + m * AROW2 + lane * 4) = pack4h(sf.x, sf.y, sf.z, sf.w);

        #pragma unroll
        for (int r = 0; r < 2; ++r) {
            const int* ir = &idxs[16 + r * 160 + m * KNEI];
            const unsigned short* Pr = P + (size_t)r * N_NODES * HID;
            float acc[8] = {0.f,0.f,0.f,0.f,0.f,0.f,0.f,0.f};
            #pragma unroll
            for (int L = 0; L < 3; ++L) {
                const int kk = L * 4 + grp;
                const int nd = ir[kk < KNEI ? kk : KNEI - 1];
                uint4 raw = *(const uint4*)(Pr + (size_t)nd * HID + l16 * 8);
                float v[8];
                union { unsigned u; _Float16 h[2]; } t;
                t.u = raw.x; v[0] = (float)t.h[0]; v[1] = (float)t.h[1];
                t.u = raw.y; v[2] = (float)t.h[0]; v[3] = (float)t.h[1];
                t.u = raw.z; v[4] = (float)t.h[0]; v[5] = (float)t.h[1];
                t.u = raw.w; v[6] = (float)t.h[0]; v[7] = (float)t.h[1];
                if (L < 2 || lane < 32) {          // mask duplicate clamp rows
                    #pragma unroll
                    for (int j = 0; j < 8; ++j) acc[j] += v[j];
                }
            }
            #pragma unroll
            for (int j = 0; j < 8; ++j) acc[j] += __shfl_xor(acc[j], 16);
            #pragma unroll
            for (int j = 0; j < 8; ++j) acc[j] += __shfl_xor(acc[j], 32);
            if (lane < 16) {
                unsigned short* d = As + m * AROW2 + 256 + r * 128 + lane * 8;
                *(ushort4*)(d)     = pack4h(acc[0]*inv, acc[1]*inv, acc[2]*inv, acc[3]*inv);
                *(ushort4*)(d + 4) = pack4h(acc[4]*inv, acc[5]*inv, acc[6]*inv, acc[7]*inv);
            }
        }
    }
    __syncthreads();

    // Phase 2: K=512 fp16 GEMM + ReLU
    const unsigned short* a_base = As + l16 * AROW2 + grp * 8;
    f32x4 acc0 = (f32x4){0.f,0.f,0.f,0.f};
    f32x4 acc1 = (f32x4){0.f,0.f,0.f,0.f};
    const int nt0 = w, nt1 = w + 4;
    #pragma unroll
    for (int kt = 0; kt < 16; ++kt) {
        half8 a = *(const half8*)(a_base + kt * 32);
        const unsigned short* bk = Bsw_det + ((size_t)(kt * 8) * 64 + lane) * 8;
        half8 b0 = *(const half8*)(bk + (size_t)nt0 * 512);
        half8 b1 = *(const half8*)(bk + (size_t)nt1 * 512);
        acc0 = __builtin_amdgcn_mfma_f32_16x16x32_f16(a, b0, acc0, 0, 0, 0);
        acc1 = __builtin_amdgcn_mfma_f32_16x16x32_f16(a, b1, acc1, 0, 0, 0);
    }
    float* orow = out + (size_t)(blk * 16) * HID;
    #pragma unroll
    for (int r = 0; r < 4; ++r) {
        const int row = grp * 4 + r;
        float v0 = acc0[r], v1 = acc1[r];
        orow[(size_t)row * HID + nt0 * 16 + l16] = v0 > 0.f ? v0 : 0.f;
        orow[(size_t)row * HID + nt1 * 16 + l16] = v1 > 0.f ? v1 : 0.f;
    }
}

// ===========================================================================
// FALLBACK PATH (round-4 verbatim, needs only 192 KB workspace)
// ===========================================================================
#define APAD    8
#define AROW    (768 + APAD)

__device__ __forceinline__ size_t bsw_index(int k, int n) {
    int kt = k >> 5, j = k & 7, hi = (k >> 3) & 3;
    int lane = hi * 16 + (n & 15), nt = n >> 4;
    return ((size_t)(kt * 8 + nt) * 64 + lane) * 8 + j;
}

__global__ __launch_bounds__(256) void prep_B_old(const float* __restrict__ W_stc,
                                                  const float* __restrict__ W_det,
                                                  unsigned short* __restrict__ Bsw) {
    const int blk = blockIdx.x;
    const int tid = threadIdx.x;
    if (blk < 256) {
        const int rel = blk >> 7;
        const int f   = (blk & 127) * 2 + (tid >> 7);
        const int n   = tid & 127;
        const float* ws = W_stc + (size_t)(rel * FEAT + f) * HID;
        const float* wd = W_det + (size_t)(256 + rel * HID) * HID + n;
        float acc = 0.f;
        #pragma unroll
        for (int j = 0; j < HID; ++j) acc += ws[j] * wd[(size_t)j * HID];
        Bsw[bsw_index(256 + rel * 256 + f, n)] = f2bf(acc);
    } else {
        const int base = (blk - 256) * 2048;
        #pragma unroll
        for (int i = 0; i < 8; ++i) {
            const int idx = base + i * 256 + tid;
            const int k = idx >> 7, n = idx & 127;
            Bsw[bsw_index(k, n)] = f2bf(W_det[idx]);
        }
    }
}

__global__ __launch_bounds__(256, 4) void fused_old(const int* __restrict__ nodes,
                                                    const int* __restrict__ neigh_idx,
                                                    const float* __restrict__ features,
                                                    const unsigned short* __restrict__ Bsw,
                                                    float* __restrict__ out) {
    __shared__ unsigned short As[16 * AROW];
    __shared__ int idxs[336];

    const int blk  = blockIdx.x;
    const int tid  = threadIdx.x;
    const int w    = tid >> 6;
    const int lane = tid & 63;
    const float inv = 1.0f / (float)KNEI;

    if (tid < 16)       idxs[tid] = nodes[blk * 16 + tid];
    else if (tid < 176) idxs[tid] = neigh_idx[blk * 160 + (tid - 16)];
    else                idxs[tid] = neigh_idx[BATCH * KNEI + blk * 160 + (tid - 176)];
    const int t2 = tid + 256;
    if (t2 < 336)       idxs[t2] = neigh_idx[BATCH * KNEI + blk * 160 + (t2 - 176)];
    __syncthreads();

    const unsigned lnoff = (unsigned)lane << 4;
    #pragma unroll
    for (int e = 0; e < 4; ++e) {
        const int m = w * 4 + e;
        int ia[11], ib[10];
        ia[0] = idxs[m];
        #pragma unroll
        for (int k = 0; k < KNEI; ++k) ia[1 + k] = idxs[16 + m * KNEI + k];
        #pragma unroll
        for (int k = 0; k < KNEI; ++k) ib[k]     = idxs[176 + m * KNEI + k];

        f32x4 ta[11];
        #pragma unroll
        for (int k = 0; k < 11; ++k) {
            const unsigned voff = ((unsigned)ia[k] << 10) + lnoff;
            asm volatile("global_load_dwordx4 %0, %1, %2"
                         : "=v"(ta[k]) : "v"(voff), "s"(features));
        }
        f32x4 tb[10];
        #pragma unroll
        for (int k = 0; k < KNEI; ++k) {
            const unsigned voff = ((unsigned)ib[k] << 10) + lnoff;
            asm volatile("global_load_dwordx4 %0, %1, %2"
                         : "=v"(tb[k]) : "v"(voff), "s"(features));
        }

        asm volatile("s_waitcnt vmcnt(10)" ::: "memory");
        __builtin_amdgcn_sched_barrier(0);

        f32x4 s0 = ta[1];
        #pragma unroll
        for (int k = 2; k < 11; ++k) s0 += ta[k];

        ushort4* row = (ushort4*)(As + m * AROW);
        row[lane]      = pack4(ta[0][0], ta[0][1], ta[0][2], ta[0][3]);
        row[64 + lane] = pack4(s0[0] * inv, s0[1] * inv, s0[2] * inv, s0[3] * inv);

        asm volatile("s_waitcnt vmcnt(0)" ::: "memory");
        __builtin_amdgcn_sched_barrier(0);

        f32x4 s1 = tb[0];
        #pragma unroll
        for (int k = 1; k < KNEI; ++k) s1 += tb[k];
        row[128 + lane] = pack4(s1[0] * inv, s1[1] * inv, s1[2] * inv, s1[3] * inv);
    }
    __syncthreads();

    const int quad = lane >> 4;
    const int l16  = lane & 15;
    const unsigned short* a_base = As + l16 * AROW + quad * 8;

    f32x4 acc0 = (f32x4){0.f, 0.f, 0.f, 0.f};
    f32x4 acc1 = (f32x4){0.f, 0.f, 0.f, 0.f};
    const int nt0 = w, nt1 = w + 4;

    #pragma unroll
    for (int kt = 0; kt < 24; ++kt) {
        bf16x8 a = *(const bf16x8*)(a_base + kt * 32);
        const unsigned short* bk = Bsw + ((size_t)(kt * 8) * 64 + lane) * 8;
        bf16x8 b0 = *(const bf16x8*)(bk + (size_t)nt0 * 64 * 8);
        bf16x8 b1 = *(const bf16x8*)(bk + (size_t)nt1 * 64 * 8);
        acc0 = __builtin_amdgcn_mfma_f32_16x16x32_bf16(a, b0, acc0, 0, 0, 0);
        acc1 = __builtin_amdgcn_mfma_f32_16x16x32_bf16(a, b1, acc1, 0, 0, 0);
    }

    float* orow = out + (size_t)(blk * 16) * HID;
    #pragma unroll
    for (int r = 0; r < 4; ++r) {
        const int row = quad * 4 + r;
        float v0 = acc0[r];
        float v1 = acc1[r];
        orow[(size_t)row * HID + nt0 * 16 + l16] = v0 > 0.f ? v0 : 0.f;
        orow[(size_t)row * HID + nt1 * 16 + l16] = v1 > 0.f ? v1 : 0.f;
    }
}

// ===========================================================================
extern "C" void kernel_launch(void* const* d_in, const int* in_sizes, int n_in,
                              void* d_out, int out_size, void* d_ws, size_t ws_size,
                              hipStream_t stream) {
    const int*   nodes     = (const int*)d_in[0];
    const int*   neigh_idx = (const int*)d_in[1];
    const float* features  = (const float*)d_in[2];
    const float* W_stc     = (const float*)d_in[3];
    const float* W_det     = (const float*)d_in[4];
    float* out = (float*)d_out;

    const size_t P_BYTES   = (size_t)REL * N_NODES * HID * 2;   // 51,200,000
    const size_t BD_BYTES  = 512 * 128 * 2;                     // 131,072
    const size_t AS_BYTES  = (size_t)REL * 32768 * 2;           // 131,072
    const size_t WS_NEEDED = P_BYTES + BD_BYTES + AS_BYTES;

    if (ws_size >= WS_NEEDED) {
        unsigned short* P       = (unsigned short*)d_ws;
        unsigned short* Bsw_det = (unsigned short*)((char*)d_ws + P_BYTES);
        unsigned short* Aswz    = (unsigned short*)((char*)d_ws + P_BYTES + BD_BYTES);
        prep_Bf16<<<96, 256, 0, stream>>>(W_stc, W_det, Bsw_det, Aswz);
        prep_P2<<<512, 256, 0, stream>>>(features, Aswz, P);
        fused2<<<BATCH / 16, 256, 0, stream>>>(nodes, neigh_idx, features, P, Bsw_det, out);
    } else {
        unsigned short* Bsw = (unsigned short*)d_ws;            // 192 KB
        prep_B_old<<<272, 256, 0, stream>>>(W_stc, W_det, Bsw);
        fused_old<<<BATCH / 16, 256, 0, stream>>>(nodes, neigh_idx, features, Bsw, out);
    }
}

// Round 8
// 216.498 us; speedup vs baseline: 1.1506x; 1.1506x over previous
//
#include <hip/hip_runtime.h>
#include <hip/hip_bf16.h>

// Problem constants (from reference)
#define N_NODES 100000
#define FEAT    256
#define HID     128
#define REL     2
#define BATCH   20000
#define KNEI    10

typedef short  bf16x8 __attribute__((ext_vector_type(8)));
typedef _Float16 half8 __attribute__((ext_vector_type(8)));
typedef float  f32x4  __attribute__((ext_vector_type(4)));

// ---------------- fp16 helpers ----------------
__device__ __forceinline__ unsigned short f2h(float x) {
    union { _Float16 h; unsigned short u; } t; t.h = (_Float16)x; return t.u;
}
__device__ __forceinline__ ushort4 pack4h(float a, float b, float c, float d) {
    ushort4 p; p.x = f2h(a); p.y = f2h(b); p.z = f2h(c); p.w = f2h(d); return p;
}

// ---------------- bf16 helpers (fallback path) ----------------
__device__ __forceinline__ unsigned short f2bf(float x) {
    union { float f; unsigned u; } v; v.f = x;
    unsigned r = v.u + 0x7fffu + ((v.u >> 16) & 1u);
    return (unsigned short)(r >> 16);
}
__device__ __forceinline__ ushort4 pack4(float a, float b, float c, float d) {
    ushort4 p; p.x = f2bf(a); p.y = f2bf(b); p.z = f2bf(c); p.w = f2bf(d); return p;
}

// Swizzled B index for logical (k, n), NT n-tiles per kt row:
//   kt=k>>5, j=k&7, hi=(k>>3)&3, lane=hi*16+(n&15), nt=n>>4
//   dest = ((kt*NT+nt)*64 + lane)*8 + j
__device__ __forceinline__ size_t bswi(int k, int n, int NT) {
    int kt = k >> 5, j = k & 7, hi = (k >> 3) & 3;
    int lane = hi * 16 + (n & 15), nt = n >> 4;
    return ((size_t)(kt * NT + nt) * 64 + lane) * 8 + j;
}

// ===========================================================================
// NEW PATH (needs ~51.5 MB workspace)
//   prep_Bf16 : W_det (512x128) -> B-swz fp16 ; W_stc (256x256 both rel) -> B-swz fp16
//   prep_P3   : P[rel][node][128] = F[node] @ W_stc[rel] — 64-node blocks,
//               register-cached B-frags, coalesced Cs-transpose stores
//   fused2    : gather self (1KB) + P rows (256B) -> K=512 fp16 GEMM + ReLU
// ===========================================================================

// blocks 0..63: Bsw_det (NT=8); blocks 64..127: Bsw_stc (NT=16) — round-6
// verified layout (prep_P consumed it correctly).
__global__ __launch_bounds__(256) void prep_Bf16(const float* __restrict__ W_stc,
                                                 const float* __restrict__ W_det,
                                                 unsigned short* __restrict__ Bsw_det,
                                                 unsigned short* __restrict__ Bsw_stc) {
    const int blk = blockIdx.x, tid = threadIdx.x;
    if (blk < 64) {
        #pragma unroll
        for (int i = 0; i < 4; ++i) {
            const int idx = blk * 1024 + i * 256 + tid;   // < 65536
            const int k = idx >> 7, n = idx & 127;
            Bsw_det[bswi(k, n, 8)] = f2h(W_det[idx]);
        }
    } else {
        #pragma unroll
        for (int i = 0; i < 4; ++i) {
            const int idx = (blk - 64) * 1024 + i * 256 + tid;  // < 65536
            const int f = idx >> 8, n = idx & 255;
            const int rel = n >> 7, h = n & 127;
            Bsw_stc[bswi(f, n, 16)] = f2h(W_stc[(size_t)(rel * FEAT + f) * HID + h]);
        }
    }
}

// prep_P3: 1563 blocks x 256 thr (4 waves). Block b: nodes [b*64, b*64+nloc).
//   Stage 64 feature rows -> fp16 LDS (one syncthreads). Wave w owns h-cols
//   [64w, 64w+64) of the N=256 output (= rel w>>1, cols (w&1)*64..+64).
//   Per kt: load wave's 4 B-frags ONCE (registers), reuse across 4 node
//   tiles -> L2 weight traffic 800 MB (round-6) -> 200 MB. C stored via
//   per-wave LDS transpose (no barrier; explicit lgkmcnt) -> 16-B contiguous
//   P stores (round-7's 8-B/256-B-stride scatter was the 1.5x write bloat).
#define APROW 264   // 256 + 8 pad (fp16 elems)
#define CSROW 68    // 64 + 4 pad (fp16 elems)
__global__ __launch_bounds__(256, 4) void prep_P3(const float* __restrict__ features,
                                                  const unsigned short* __restrict__ Bsw_stc,
                                                  unsigned short* __restrict__ P) {
    __shared__ __align__(16) unsigned short Ap[64 * APROW];      // 33792 B
    __shared__ __align__(16) unsigned short Cs[4][16 * CSROW];   // 8704 B

    const int blk = blockIdx.x, tid = threadIdx.x;
    const int w = tid >> 6, lane = tid & 63;
    const int q = lane >> 4, l16 = lane & 15;
    const int base = blk * 64;
    const int nloc = (N_NODES - base) < 64 ? (N_NODES - base) : 64;  // 64 or 32
    const int ntile = nloc >> 4;
    const float4* F4 = (const float4*)features;

    // ---- stage 64 feature rows (fp32 -> fp16), coalesced ----
    #pragma unroll
    for (int i = 0; i < 16; ++i) {
        const int g = i * 256 + tid;            // 0..4095
        const int row = g >> 6, c4 = g & 63;
        if (row < nloc) {
            float4 v = F4[(size_t)(base + row) * 64 + c4];
            *(ushort4*)(Ap + row * APROW + c4 * 4) = pack4h(v.x, v.y, v.z, v.w);
        }
    }
    __syncthreads();

    // ---- MFMA: acc[tile][t4], B-frags loaded once per kt ----
    f32x4 acc[4][4];
    #pragma unroll
    for (int t = 0; t < 4; ++t)
        #pragma unroll
        for (int j = 0; j < 4; ++j) acc[t][j] = (f32x4){0.f, 0.f, 0.f, 0.f};

    #pragma unroll
    for (int kt = 0; kt < 8; ++kt) {
        half8 bb[4];
        #pragma unroll
        for (int t4 = 0; t4 < 4; ++t4) {
            const int nt = w * 4 + t4;
            bb[t4] = *(const half8*)(Bsw_stc + ((size_t)(kt * 16 + nt) * 64 + lane) * 8);
        }
        #pragma unroll
        for (int tile = 0; tile < 4; ++tile) {
            half8 a = *(const half8*)(Ap + (tile * 16 + l16) * APROW + kt * 32 + q * 8);
            #pragma unroll
            for (int t4 = 0; t4 < 4; ++t4)
                acc[tile][t4] = __builtin_amdgcn_mfma_f32_16x16x32_f16(a, bb[t4], acc[tile][t4], 0, 0, 0);
        }
    }

    // ---- per-wave Cs transpose -> coalesced P stores ----
    const int rel_w = w >> 1;
    const int colbase = (w & 1) * 64;           // within-rel col (halves)
    unsigned short* Pw = P + (size_t)rel_w * N_NODES * HID;
    unsigned short* Cw = Cs[w];
    const int nl = lane >> 2, seg = lane & 3;

    #pragma unroll
    for (int tile = 0; tile < 4; ++tile) {
        // C[m=node-local (q*4+r)][n=wave-col (t4*16+l16)]
        #pragma unroll
        for (int t4 = 0; t4 < 4; ++t4)
            #pragma unroll
            for (int r = 0; r < 4; ++r)
                Cw[(q * 4 + r) * CSROW + t4 * 16 + l16] = f2h(acc[tile][t4][r]);
        asm volatile("s_waitcnt lgkmcnt(0)" ::: "memory");
        __builtin_amdgcn_sched_barrier(0);

        if (tile < ntile) {
            const int gnode = base + tile * 16 + nl;
            const unsigned short* src = Cw + nl * CSROW + seg * 16;
            unsigned short* dst = Pw + (size_t)gnode * HID + colbase + seg * 16;
            *(uint4*)(dst)     = *(const uint4*)(src);      // halves 0..7
            *(uint4*)(dst + 8) = *(const uint4*)(src + 8);  // halves 8..15
        }
    }
}

// fused2: A row = [self fp16 (256) | meanP0 (128) | meanP1 (128)], K=512.
#define AROW2 520   // 512 + 8 pad (fp16 elems)
__global__ __launch_bounds__(256, 6) void fused2(const int* __restrict__ nodes,
                                                 const int* __restrict__ neigh_idx,
                                                 const float* __restrict__ features,
                                                 const unsigned short* __restrict__ P,
                                                 const unsigned short* __restrict__ Bsw_det,
                                                 float* __restrict__ out) {
    __shared__ __align__(16) unsigned short As[16 * AROW2];  // 16640 B
    __shared__ int idxs[336];

    const int blk = blockIdx.x, tid = threadIdx.x;
    const int w = tid >> 6, lane = tid & 63;
    const int grp = lane >> 4, l16 = lane & 15;
    const float4* F4 = (const float4*)features;
    const float inv = 1.0f / (float)KNEI;

    // Phase 0: stage indices
    if (tid < 16)       idxs[tid] = nodes[blk * 16 + tid];
    else if (tid < 176) idxs[tid] = neigh_idx[blk * 160 + (tid - 16)];
    else                idxs[tid] = neigh_idx[BATCH * KNEI + blk * 160 + (tid - 176)];
    const int t2 = tid + 256;
    if (t2 < 336)       idxs[t2] = neigh_idx[BATCH * KNEI + blk * 160 + (t2 - 176)];
    __syncthreads();

    // Phase 1: self gather (1KB f32) + P-row gather (256B fp16, 4 rows/load)
    #pragma unroll
    for (int e = 0; e < 4; ++e) {
        const int m = w * 4 + e;
        float4 sf = F4[(size_t)idxs[m] * 64 + lane];
        *(ushort4*)(As + m * AROW2 + lane * 4) = pack4h(sf.x, sf.y, sf.z, sf.w);

        #pragma unroll
        for (int r = 0; r < 2; ++r) {
            const int* ir = &idxs[16 + r * 160 + m * KNEI];
            const unsigned short* Pr = P + (size_t)r * N_NODES * HID;
            float acc[8] = {0.f,0.f,0.f,0.f,0.f,0.f,0.f,0.f};
            #pragma unroll
            for (int L = 0; L < 3; ++L) {
                const int kk = L * 4 + grp;
                const int nd = ir[kk < KNEI ? kk : KNEI - 1];
                uint4 raw = *(const uint4*)(Pr + (size_t)nd * HID + l16 * 8);
                float v[8];
                union { unsigned u; _Float16 h[2]; } t;
                t.u = raw.x; v[0] = (float)t.h[0]; v[1] = (float)t.h[1];
                t.u = raw.y; v[2] = (float)t.h[0]; v[3] = (float)t.h[1];
                t.u = raw.z; v[4] = (float)t.h[0]; v[5] = (float)t.h[1];
                t.u = raw.w; v[6] = (float)t.h[0]; v[7] = (float)t.h[1];
                if (L < 2 || lane < 32) {          // mask duplicate clamp rows
                    #pragma unroll
                    for (int j = 0; j < 8; ++j) acc[j] += v[j];
                }
            }
            #pragma unroll
            for (int j = 0; j < 8; ++j) acc[j] += __shfl_xor(acc[j], 16);
            #pragma unroll
            for (int j = 0; j < 8; ++j) acc[j] += __shfl_xor(acc[j], 32);
            if (lane < 16) {
                unsigned short* d = As + m * AROW2 + 256 + r * 128 + lane * 8;
                *(ushort4*)(d)     = pack4h(acc[0]*inv, acc[1]*inv, acc[2]*inv, acc[3]*inv);
                *(ushort4*)(d + 4) = pack4h(acc[4]*inv, acc[5]*inv, acc[6]*inv, acc[7]*inv);
            }
        }
    }
    __syncthreads();

    // Phase 2: K=512 fp16 GEMM + ReLU
    const unsigned short* a_base = As + l16 * AROW2 + grp * 8;
    f32x4 acc0 = (f32x4){0.f,0.f,0.f,0.f};
    f32x4 acc1 = (f32x4){0.f,0.f,0.f,0.f};
    const int nt0 = w, nt1 = w + 4;
    #pragma unroll
    for (int kt = 0; kt < 16; ++kt) {
        half8 a = *(const half8*)(a_base + kt * 32);
        const unsigned short* bk = Bsw_det + ((size_t)(kt * 8) * 64 + lane) * 8;
        half8 b0 = *(const half8*)(bk + (size_t)nt0 * 512);
        half8 b1 = *(const half8*)(bk + (size_t)nt1 * 512);
        acc0 = __builtin_amdgcn_mfma_f32_16x16x32_f16(a, b0, acc0, 0, 0, 0);
        acc1 = __builtin_amdgcn_mfma_f32_16x16x32_f16(a, b1, acc1, 0, 0, 0);
    }
    float* orow = out + (size_t)(blk * 16) * HID;
    #pragma unroll
    for (int r = 0; r < 4; ++r) {
        const int row = grp * 4 + r;
        float v0 = acc0[r], v1 = acc1[r];
        orow[(size_t)row * HID + nt0 * 16 + l16] = v0 > 0.f ? v0 : 0.f;
        orow[(size_t)row * HID + nt1 * 16 + l16] = v1 > 0.f ? v1 : 0.f;
    }
}

// ===========================================================================
// FALLBACK PATH (round-4 verbatim, needs only 192 KB workspace)
// ===========================================================================
#define APAD    8
#define AROW    (768 + APAD)

__device__ __forceinline__ size_t bsw_index(int k, int n) {
    int kt = k >> 5, j = k & 7, hi = (k >> 3) & 3;
    int lane = hi * 16 + (n & 15), nt = n >> 4;
    return ((size_t)(kt * 8 + nt) * 64 + lane) * 8 + j;
}

__global__ __launch_bounds__(256) void prep_B_old(const float* __restrict__ W_stc,
                                                  const float* __restrict__ W_det,
                                                  unsigned short* __restrict__ Bsw) {
    const int blk = blockIdx.x;
    const int tid = threadIdx.x;
    if (blk < 256) {
        const int rel = blk >> 7;
        const int f   = (blk & 127) * 2 + (tid >> 7);
        const int n   = tid & 127;
        const float* ws = W_stc + (size_t)(rel * FEAT + f) * HID;
        const float* wd = W_det + (size_t)(256 + rel * HID) * HID + n;
        float acc = 0.f;
        #pragma unroll
        for (int j = 0; j < HID; ++j) acc += ws[j] * wd[(size_t)j * HID];
        Bsw[bsw_index(256 + rel * 256 + f, n)] = f2bf(acc);
    } else {
        const int base = (blk - 256) * 2048;
        #pragma unroll
        for (int i = 0; i < 8; ++i) {
            const int idx = base + i * 256 + tid;
            const int k = idx >> 7, n = idx & 127;
            Bsw[bsw_index(k, n)] = f2bf(W_det[idx]);
        }
    }
}

__global__ __launch_bounds__(256, 4) void fused_old(const int* __restrict__ nodes,
                                                    const int* __restrict__ neigh_idx,
                                                    const float* __restrict__ features,
                                                    const unsigned short* __restrict__ Bsw,
                                                    float* __restrict__ out) {
    __shared__ unsigned short As[16 * AROW];
    __shared__ int idxs[336];

    const int blk  = blockIdx.x;
    const int tid  = threadIdx.x;
    const int w    = tid >> 6;
    const int lane = tid & 63;
    const float inv = 1.0f / (float)KNEI;

    if (tid < 16)       idxs[tid] = nodes[blk * 16 + tid];
    else if (tid < 176) idxs[tid] = neigh_idx[blk * 160 + (tid - 16)];
    else                idxs[tid] = neigh_idx[BATCH * KNEI + blk * 160 + (tid - 176)];
    const int t2 = tid + 256;
    if (t2 < 336)       idxs[t2] = neigh_idx[BATCH * KNEI + blk * 160 + (t2 - 176)];
    __syncthreads();

    const unsigned lnoff = (unsigned)lane << 4;
    #pragma unroll
    for (int e = 0; e < 4; ++e) {
        const int m = w * 4 + e;
        int ia[11], ib[10];
        ia[0] = idxs[m];
        #pragma unroll
        for (int k = 0; k < KNEI; ++k) ia[1 + k] = idxs[16 + m * KNEI + k];
        #pragma unroll
        for (int k = 0; k < KNEI; ++k) ib[k]     = idxs[176 + m * KNEI + k];

        f32x4 ta[11];
        #pragma unroll
        for (int k = 0; k < 11; ++k) {
            const unsigned voff = ((unsigned)ia[k] << 10) + lnoff;
            asm volatile("global_load_dwordx4 %0, %1, %2"
                         : "=v"(ta[k]) : "v"(voff), "s"(features));
        }
        f32x4 tb[10];
        #pragma unroll
        for (int k = 0; k < KNEI; ++k) {
            const unsigned voff = ((unsigned)ib[k] << 10) + lnoff;
            asm volatile("global_load_dwordx4 %0, %1, %2"
                         : "=v"(tb[k]) : "v"(voff), "s"(features));
        }

        asm volatile("s_waitcnt vmcnt(10)" ::: "memory");
        __builtin_amdgcn_sched_barrier(0);

        f32x4 s0 = ta[1];
        #pragma unroll
        for (int k = 2; k < 11; ++k) s0 += ta[k];

        ushort4* row = (ushort4*)(As + m * AROW);
        row[lane]      = pack4(ta[0][0], ta[0][1], ta[0][2], ta[0][3]);
        row[64 + lane] = pack4(s0[0] * inv, s0[1] * inv, s0[2] * inv, s0[3] * inv);

        asm volatile("s_waitcnt vmcnt(0)" ::: "memory");
        __builtin_amdgcn_sched_barrier(0);

        f32x4 s1 = tb[0];
        #pragma unroll
        for (int k = 1; k < KNEI; ++k) s1 += tb[k];
        row[128 + lane] = pack4(s1[0] * inv, s1[1] * inv, s1[2] * inv, s1[3] * inv);
    }
    __syncthreads();

    const int quad = lane >> 4;
    const int l16  = lane & 15;
    const unsigned short* a_base = As + l16 * AROW + quad * 8;

    f32x4 acc0 = (f32x4){0.f, 0.f, 0.f, 0.f};
    f32x4 acc1 = (f32x4){0.f, 0.f, 0.f, 0.f};
    const int nt0 = w, nt1 = w + 4;

    #pragma unroll
    for (int kt = 0; kt < 24; ++kt) {
        bf16x8 a = *(const bf16x8*)(a_base + kt * 32);
        const unsigned short* bk = Bsw + ((size_t)(kt * 8) * 64 + lane) * 8;
        bf16x8 b0 = *(const bf16x8*)(bk + (size_t)nt0 * 64 * 8);
        bf16x8 b1 = *(const bf16x8*)(bk + (size_t)nt1 * 64 * 8);
        acc0 = __builtin_amdgcn_mfma_f32_16x16x32_bf16(a, b0, acc0, 0, 0, 0);
        acc1 = __builtin_amdgcn_mfma_f32_16x16x32_bf16(a, b1, acc1, 0, 0, 0);
    }

    float* orow = out + (size_t)(blk * 16) * HID;
    #pragma unroll
    for (int r = 0; r < 4; ++r) {
        const int row = quad * 4 + r;
        float v0 = acc0[r];
        float v1 = acc1[r];
        orow[(size_t)row * HID + nt0 * 16 + l16] = v0 > 0.f ? v0 : 0.f;
        orow[(size_t)row * HID + nt1 * 16 + l16] = v1 > 0.f ? v1 : 0.f;
    }
}

// ===========================================================================
extern "C" void kernel_launch(void* const* d_in, const int* in_sizes, int n_in,
                              void* d_out, int out_size, void* d_ws, size_t ws_size,
                              hipStream_t stream) {
    const int*   nodes     = (const int*)d_in[0];
    const int*   neigh_idx = (const int*)d_in[1];
    const float* features  = (const float*)d_in[2];
    const float* W_stc     = (const float*)d_in[3];
    const float* W_det     = (const float*)d_in[4];
    float* out = (float*)d_out;

    const size_t P_BYTES   = (size_t)REL * N_NODES * HID * 2;   // 51,200,000
    const size_t BD_BYTES  = 512 * 128 * 2;                     // 131,072
    const size_t BS_BYTES  = 256 * 256 * 2;                     // 131,072
    const size_t WS_NEEDED = P_BYTES + BD_BYTES + BS_BYTES;

    if (ws_size >= WS_NEEDED) {
        unsigned short* P       = (unsigned short*)d_ws;
        unsigned short* Bsw_det = (unsigned short*)((char*)d_ws + P_BYTES);
        unsigned short* Bsw_stc = (unsigned short*)((char*)d_ws + P_BYTES + BD_BYTES);
        prep_Bf16<<<128, 256, 0, stream>>>(W_stc, W_det, Bsw_det, Bsw_stc);
        prep_P3<<<(N_NODES + 63) / 64, 256, 0, stream>>>(features, Bsw_stc, P);
        fused2<<<BATCH / 16, 256, 0, stream>>>(nodes, neigh_idx, features, P, Bsw_det, out);
    } else {
        unsigned short* Bsw = (unsigned short*)d_ws;            // 192 KB
        prep_B_old<<<272, 256, 0, stream>>>(W_stc, W_det, Bsw);
        fused_old<<<BATCH / 16, 256, 0, stream>>>(nodes, neigh_idx, features, Bsw, out);
    }
}

// Round 9
// 216.359 us; speedup vs baseline: 1.1513x; 1.0006x over previous
//
#include <hip/hip_runtime.h>
#include <hip/hip_bf16.h>

// Problem constants (from reference)
#define N_NODES 100000
#define FEAT    256
#define HID     128
#define REL     2
#define BATCH   20000
#define KNEI    10

typedef short  bf16x8 __attribute__((ext_vector_type(8)));
typedef _Float16 half8 __attribute__((ext_vector_type(8)));
typedef float  f32x4  __attribute__((ext_vector_type(4)));

// ---------------- fp16 helpers ----------------
__device__ __forceinline__ unsigned short f2h(float x) {
    union { _Float16 h; unsigned short u; } t; t.h = (_Float16)x; return t.u;
}
__device__ __forceinline__ ushort4 pack4h(float a, float b, float c, float d) {
    ushort4 p; p.x = f2h(a); p.y = f2h(b); p.z = f2h(c); p.w = f2h(d); return p;
}

// ---------------- bf16 helpers (fallback path) ----------------
__device__ __forceinline__ unsigned short f2bf(float x) {
    union { float f; unsigned u; } v; v.f = x;
    unsigned r = v.u + 0x7fffu + ((v.u >> 16) & 1u);
    return (unsigned short)(r >> 16);
}
__device__ __forceinline__ ushort4 pack4(float a, float b, float c, float d) {
    ushort4 p; p.x = f2bf(a); p.y = f2bf(b); p.z = f2bf(c); p.w = f2bf(d); return p;
}

// Swizzled B index for logical (k, n), NT n-tiles per kt row:
//   kt=k>>5, j=k&7, hi=(k>>3)&3, lane=hi*16+(n&15), nt=n>>4
//   dest = ((kt*NT+nt)*64 + lane)*8 + j
__device__ __forceinline__ size_t bswi(int k, int n, int NT) {
    int kt = k >> 5, j = k & 7, hi = (k >> 3) & 3;
    int lane = hi * 16 + (n & 15), nt = n >> 4;
    return ((size_t)(kt * NT + nt) * 64 + lane) * 8 + j;
}

// ===========================================================================
// NEW PATH (needs ~51.5 MB workspace)
//   prep_Bf16 : W_det (512x128) -> B-swz fp16 ; W_stc (256x256 both rel) -> B-swz fp16
//   prep_P4   : P[rel][node][128] = F[node] @ W_stc[rel] — 512-thr blocks,
//               32-VGPR acc, B double-buffer, 24 waves/CU
//   fused2    : gather self (1KB) + P rows (256B) -> K=512 fp16 GEMM + ReLU
// ===========================================================================

// blocks 0..63: Bsw_det (NT=8); blocks 64..127: Bsw_stc (NT=16) — verified
// layouts (rounds 6-8 consumed them correctly).
__global__ __launch_bounds__(256) void prep_Bf16(const float* __restrict__ W_stc,
                                                 const float* __restrict__ W_det,
                                                 unsigned short* __restrict__ Bsw_det,
                                                 unsigned short* __restrict__ Bsw_stc) {
    const int blk = blockIdx.x, tid = threadIdx.x;
    if (blk < 64) {
        #pragma unroll
        for (int i = 0; i < 4; ++i) {
            const int idx = blk * 1024 + i * 256 + tid;   // < 65536
            const int k = idx >> 7, n = idx & 127;
            Bsw_det[bswi(k, n, 8)] = f2h(W_det[idx]);
        }
    } else {
        #pragma unroll
        for (int i = 0; i < 4; ++i) {
            const int idx = (blk - 64) * 1024 + i * 256 + tid;  // < 65536
            const int f = idx >> 8, n = idx & 255;
            const int rel = n >> 7, h = n & 127;
            Bsw_stc[bswi(f, n, 16)] = f2h(W_stc[(size_t)(rel * FEAT + f) * HID + h]);
        }
    }
}

// prep_P4: 1563 blocks x 512 thr (8 waves). Block b: nodes [b*64, b*64+nloc).
//   Round-8 post-mortem: acc[4][4]=64 VGPR + 42.5 KB LDS left 8 waves/CU and
//   no prefetch headroom -> latency-bound at 70 us with minimal traffic.
//   Here: wave w owns 2 n-tiles {2w, 2w+1} x 4 node-tiles -> acc[4][2] =
//   32 VGPR; explicit kt+1 B-frag double-buffer; LDS 44 KB -> 3 blocks/CU
//   = 24 waves/CU. Store path: per-wave Cs transpose (CSROW=40: 4-row
//   stride 80 dwords = 16 mod 32 -> conflict-free q-banking; 16-B-aligned
//   reads), each 4-lane group writes one full 64-B line of a P row.
#define APROW 264   // 256 + 8 pad (fp16 elems)
#define CSW   40    // 32 + 8 pad (fp16 elems), 16-B aligned rows
__global__ __launch_bounds__(512, 6) void prep_P4(const float* __restrict__ features,
                                                  const unsigned short* __restrict__ Bsw_stc,
                                                  unsigned short* __restrict__ P) {
    __shared__ __align__(16) unsigned short Ap[64 * APROW];      // 33792 B
    __shared__ __align__(16) unsigned short Cs[8][16 * CSW];     // 10240 B

    const int blk = blockIdx.x, tid = threadIdx.x;
    const int w = tid >> 6, lane = tid & 63;
    const int q = lane >> 4, l16 = lane & 15;
    const int base = blk * 64;
    const int nloc = (N_NODES - base) < 64 ? (N_NODES - base) : 64;  // 64 or 32
    const int ntile = nloc >> 4;
    const float4* F4 = (const float4*)features;

    // ---- stage feature rows (fp32 -> fp16), coalesced: 8 x 512 thr ----
    #pragma unroll
    for (int i = 0; i < 8; ++i) {
        const int g = i * 512 + tid;            // 0..4095
        const int row = g >> 6, c4 = g & 63;
        if (row < nloc) {
            float4 v = F4[(size_t)(base + row) * 64 + c4];
            *(ushort4*)(Ap + row * APROW + c4 * 4) = pack4h(v.x, v.y, v.z, v.w);
        }
    }
    __syncthreads();

    // ---- MFMA: acc[tile][t4], B-frags double-buffered across kt ----
    const int nt0 = w * 2, nt1 = w * 2 + 1;
    f32x4 acc[4][2];
    #pragma unroll
    for (int t = 0; t < 4; ++t) {
        acc[t][0] = (f32x4){0.f, 0.f, 0.f, 0.f};
        acc[t][1] = (f32x4){0.f, 0.f, 0.f, 0.f};
    }

    half8 bb0 = *(const half8*)(Bsw_stc + ((size_t)(0 * 16 + nt0) * 64 + lane) * 8);
    half8 bb1 = *(const half8*)(Bsw_stc + ((size_t)(0 * 16 + nt1) * 64 + lane) * 8);
    #pragma unroll
    for (int kt = 0; kt < 8; ++kt) {
        half8 bn0, bn1;
        if (kt < 7) {
            bn0 = *(const half8*)(Bsw_stc + ((size_t)((kt + 1) * 16 + nt0) * 64 + lane) * 8);
            bn1 = *(const half8*)(Bsw_stc + ((size_t)((kt + 1) * 16 + nt1) * 64 + lane) * 8);
        }
        #pragma unroll
        for (int tile = 0; tile < 4; ++tile) {
            half8 a = *(const half8*)(Ap + (tile * 16 + l16) * APROW + kt * 32 + q * 8);
            acc[tile][0] = __builtin_amdgcn_mfma_f32_16x16x32_f16(a, bb0, acc[tile][0], 0, 0, 0);
            acc[tile][1] = __builtin_amdgcn_mfma_f32_16x16x32_f16(a, bb1, acc[tile][1], 0, 0, 0);
        }
        bb0 = bn0; bb1 = bn1;
    }

    // ---- per-wave Cs transpose -> coalesced P stores ----
    const int rel_w = w >> 2;
    const int colbase = (w & 3) * 32;           // within-rel col (halves)
    unsigned short* Pw = P + (size_t)rel_w * N_NODES * HID;
    unsigned short* Cw = Cs[w];
    const int nl = lane >> 2, seg = lane & 3;

    #pragma unroll
    for (int tile = 0; tile < 4; ++tile) {
        // C[m=node-local (q*4+r)][n=wave-col (t4*16+l16)]
        #pragma unroll
        for (int t4 = 0; t4 < 2; ++t4)
            #pragma unroll
            for (int r = 0; r < 4; ++r)
                Cw[(q * 4 + r) * CSW + t4 * 16 + l16] = f2h(acc[tile][t4][r]);
        asm volatile("s_waitcnt lgkmcnt(0)" ::: "memory");
        __builtin_amdgcn_sched_barrier(0);

        if (tile < ntile) {
            const int gnode = base + tile * 16 + nl;
            const unsigned short* src = Cw + nl * CSW + seg * 8;
            unsigned short* dst = Pw + (size_t)gnode * HID + colbase + seg * 8;
            *(uint4*)(dst) = *(const uint4*)(src);      // 16 B; 4 lanes = 64-B line
        }
        __builtin_amdgcn_sched_barrier(0);
    }
}

// fused2: A row = [self fp16 (256) | meanP0 (128) | meanP1 (128)], K=512.
#define AROW2 520   // 512 + 8 pad (fp16 elems)
__global__ __launch_bounds__(256, 6) void fused2(const int* __restrict__ nodes,
                                                 const int* __restrict__ neigh_idx,
                                                 const float* __restrict__ features,
                                                 const unsigned short* __restrict__ P,
                                                 const unsigned short* __restrict__ Bsw_det,
                                                 float* __restrict__ out) {
    __shared__ __align__(16) unsigned short As[16 * AROW2];  // 16640 B
    __shared__ int idxs[336];

    const int blk = blockIdx.x, tid = threadIdx.x;
    const int w = tid >> 6, lane = tid & 63;
    const int grp = lane >> 4, l16 = lane & 15;
    const float4* F4 = (const float4*)features;
    const float inv = 1.0f / (float)KNEI;

    // Phase 0: stage indices
    if (tid < 16)       idxs[tid] = nodes[blk * 16 + tid];
    else if (tid < 176) idxs[tid] = neigh_idx[blk * 160 + (tid - 16)];
    else                idxs[tid] = neigh_idx[BATCH * KNEI + blk * 160 + (tid - 176)];
    const int t2 = tid + 256;
    if (t2 < 336)       idxs[t2] = neigh_idx[BATCH * KNEI + blk * 160 + (t2 - 176)];
    __syncthreads();

    // Phase 1: self gather (1KB f32) + P-row gather (256B fp16, 4 rows/load)
    #pragma unroll
    for (int e = 0; e < 4; ++e) {
        const int m = w * 4 + e;
        float4 sf = F4[(size_t)idxs[m] * 64 + lane];
        *(ushort4*)(As + m * AROW2 + lane * 4) = pack4h(sf.x, sf.y, sf.z, sf.w);

        #pragma unroll
        for (int r = 0; r < 2; ++r) {
            const int* ir = &idxs[16 + r * 160 + m * KNEI];
            const unsigned short* Pr = P + (size_t)r * N_NODES * HID;
            float acc[8] = {0.f,0.f,0.f,0.f,0.f,0.f,0.f,0.f};
            #pragma unroll
            for (int L = 0; L < 3; ++L) {
                const int kk = L * 4 + grp;
                const int nd = ir[kk < KNEI ? kk : KNEI - 1];
                uint4 raw = *(const uint4*)(Pr + (size_t)nd * HID + l16 * 8);
                float v[8];
                union { unsigned u; _Float16 h[2]; } t;
                t.u = raw.x; v[0] = (float)t.h[0]; v[1] = (float)t.h[1];
                t.u = raw.y; v[2] = (float)t.h[0]; v[3] = (float)t.h[1];
                t.u = raw.z; v[4] = (float)t.h[0]; v[5] = (float)t.h[1];
                t.u = raw.w; v[6] = (float)t.h[0]; v[7] = (float)t.h[1];
                if (L < 2 || lane < 32) {          // mask duplicate clamp rows
                    #pragma unroll
                    for (int j = 0; j < 8; ++j) acc[j] += v[j];
                }
            }
            #pragma unroll
            for (int j = 0; j < 8; ++j) acc[j] += __shfl_xor(acc[j], 16);
            #pragma unroll
            for (int j = 0; j < 8; ++j) acc[j] += __shfl_xor(acc[j], 32);
            if (lane < 16) {
                unsigned short* d = As + m * AROW2 + 256 + r * 128 + lane * 8;
                *(ushort4*)(d)     = pack4h(acc[0]*inv, acc[1]*inv, acc[2]*inv, acc[3]*inv);
                *(ushort4*)(d + 4) = pack4h(acc[4]*inv, acc[5]*inv, acc[6]*inv, acc[7]*inv);
            }
        }
    }
    __syncthreads();

    // Phase 2: K=512 fp16 GEMM + ReLU
    const unsigned short* a_base = As + l16 * AROW2 + grp * 8;
    f32x4 acc0 = (f32x4){0.f,0.f,0.f,0.f};
    f32x4 acc1 = (f32x4){0.f,0.f,0.f,0.f};
    const int nt0 = w, nt1 = w + 4;
    #pragma unroll
    for (int kt = 0; kt < 16; ++kt) {
        half8 a = *(const half8*)(a_base + kt * 32);
        const unsigned short* bk = Bsw_det + ((size_t)(kt * 8) * 64 + lane) * 8;
        half8 b0 = *(const half8*)(bk + (size_t)nt0 * 512);
        half8 b1 = *(const half8*)(bk + (size_t)nt1 * 512);
        acc0 = __builtin_amdgcn_mfma_f32_16x16x32_f16(a, b0, acc0, 0, 0, 0);
        acc1 = __builtin_amdgcn_mfma_f32_16x16x32_f16(a, b1, acc1, 0, 0, 0);
    }
    float* orow = out + (size_t)(blk * 16) * HID;
    #pragma unroll
    for (int r = 0; r < 4; ++r) {
        const int row = grp * 4 + r;
        float v0 = acc0[r], v1 = acc1[r];
        orow[(size_t)row * HID + nt0 * 16 + l16] = v0 > 0.f ? v0 : 0.f;
        orow[(size_t)row * HID + nt1 * 16 + l16] = v1 > 0.f ? v1 : 0.f;
    }
}

// ===========================================================================
// FALLBACK PATH (round-4 verbatim, needs only 192 KB workspace)
// ===========================================================================
#define APAD    8
#define AROW    (768 + APAD)

__device__ __forceinline__ size_t bsw_index(int k, int n) {
    int kt = k >> 5, j = k & 7, hi = (k >> 3) & 3;
    int lane = hi * 16 + (n & 15), nt = n >> 4;
    return ((size_t)(kt * 8 + nt) * 64 + lane) * 8 + j;
}

__global__ __launch_bounds__(256) void prep_B_old(const float* __restrict__ W_stc,
                                                  const float* __restrict__ W_det,
                                                  unsigned short* __restrict__ Bsw) {
    const int blk = blockIdx.x;
    const int tid = threadIdx.x;
    if (blk < 256) {
        const int rel = blk >> 7;
        const int f   = (blk & 127) * 2 + (tid >> 7);
        const int n   = tid & 127;
        const float* ws = W_stc + (size_t)(rel * FEAT + f) * HID;
        const float* wd = W_det + (size_t)(256 + rel * HID) * HID + n;
        float acc = 0.f;
        #pragma unroll
        for (int j = 0; j < HID; ++j) acc += ws[j] * wd[(size_t)j * HID];
        Bsw[bsw_index(256 + rel * 256 + f, n)] = f2bf(acc);
    } else {
        const int base = (blk - 256) * 2048;
        #pragma unroll
        for (int i = 0; i < 8; ++i) {
            const int idx = base + i * 256 + tid;
            const int k = idx >> 7, n = idx & 127;
            Bsw[bsw_index(k, n)] = f2bf(W_det[idx]);
        }
    }
}

__global__ __launch_bounds__(256, 4) void fused_old(const int* __restrict__ nodes,
                                                    const int* __restrict__ neigh_idx,
                                                    const float* __restrict__ features,
                                                    const unsigned short* __restrict__ Bsw,
                                                    float* __restrict__ out) {
    __shared__ unsigned short As[16 * AROW];
    __shared__ int idxs[336];

    const int blk  = blockIdx.x;
    const int tid  = threadIdx.x;
    const int w    = tid >> 6;
    const int lane = tid & 63;
    const float inv = 1.0f / (float)KNEI;

    if (tid < 16)       idxs[tid] = nodes[blk * 16 + tid];
    else if (tid < 176) idxs[tid] = neigh_idx[blk * 160 + (tid - 16)];
    else                idxs[tid] = neigh_idx[BATCH * KNEI + blk * 160 + (tid - 176)];
    const int t2 = tid + 256;
    if (t2 < 336)       idxs[t2] = neigh_idx[BATCH * KNEI + blk * 160 + (t2 - 176)];
    __syncthreads();

    const unsigned lnoff = (unsigned)lane << 4;
    #pragma unroll
    for (int e = 0; e < 4; ++e) {
        const int m = w * 4 + e;
        int ia[11], ib[10];
        ia[0] = idxs[m];
        #pragma unroll
        for (int k = 0; k < KNEI; ++k) ia[1 + k] = idxs[16 + m * KNEI + k];
        #pragma unroll
        for (int k = 0; k < KNEI; ++k) ib[k]     = idxs[176 + m * KNEI + k];

        f32x4 ta[11];
        #pragma unroll
        for (int k = 0; k < 11; ++k) {
            const unsigned voff = ((unsigned)ia[k] << 10) + lnoff;
            asm volatile("global_load_dwordx4 %0, %1, %2"
                         : "=v"(ta[k]) : "v"(voff), "s"(features));
        }
        f32x4 tb[10];
        #pragma unroll
        for (int k = 0; k < KNEI; ++k) {
            const unsigned voff = ((unsigned)ib[k] << 10) + lnoff;
            asm volatile("global_load_dwordx4 %0, %1, %2"
                         : "=v"(tb[k]) : "v"(voff), "s"(features));
        }

        asm volatile("s_waitcnt vmcnt(10)" ::: "memory");
        __builtin_amdgcn_sched_barrier(0);

        f32x4 s0 = ta[1];
        #pragma unroll
        for (int k = 2; k < 11; ++k) s0 += ta[k];

        ushort4* row = (ushort4*)(As + m * AROW);
        row[lane]      = pack4(ta[0][0], ta[0][1], ta[0][2], ta[0][3]);
        row[64 + lane] = pack4(s0[0] * inv, s0[1] * inv, s0[2] * inv, s0[3] * inv);

        asm volatile("s_waitcnt vmcnt(0)" ::: "memory");
        __builtin_amdgcn_sched_barrier(0);

        f32x4 s1 = tb[0];
        #pragma unroll
        for (int k = 1; k < KNEI; ++k) s1 += tb[k];
        row[128 + lane] = pack4(s1[0] * inv, s1[1] * inv, s1[2] * inv, s1[3] * inv);
    }
    __syncthreads();

    const int quad = lane >> 4;
    const int l16  = lane & 15;
    const unsigned short* a_base = As + l16 * AROW + quad * 8;

    f32x4 acc0 = (f32x4){0.f, 0.f, 0.f, 0.f};
    f32x4 acc1 = (f32x4){0.f, 0.f, 0.f, 0.f};
    const int nt0 = w, nt1 = w + 4;

    #pragma unroll
    for (int kt = 0; kt < 24; ++kt) {
        bf16x8 a = *(const bf16x8*)(a_base + kt * 32);
        const unsigned short* bk = Bsw + ((size_t)(kt * 8) * 64 + lane) * 8;
        bf16x8 b0 = *(const bf16x8*)(bk + (size_t)nt0 * 64 * 8);
        bf16x8 b1 = *(const bf16x8*)(bk + (size_t)nt1 * 64 * 8);
        acc0 = __builtin_amdgcn_mfma_f32_16x16x32_bf16(a, b0, acc0, 0, 0, 0);
        acc1 = __builtin_amdgcn_mfma_f32_16x16x32_bf16(a, b1, acc1, 0, 0, 0);
    }

    float* orow = out + (size_t)(blk * 16) * HID;
    #pragma unroll
    for (int r = 0; r < 4; ++r) {
        const int row = quad * 4 + r;
        float v0 = acc0[r];
        float v1 = acc1[r];
        orow[(size_t)row * HID + nt0 * 16 + l16] = v0 > 0.f ? v0 : 0.f;
        orow[(size_t)row * HID + nt1 * 16 + l16] = v1 > 0.f ? v1 : 0.f;
    }
}

// ===========================================================================
extern "C" void kernel_launch(void* const* d_in, const int* in_sizes, int n_in,
                              void* d_out, int out_size, void* d_ws, size_t ws_size,
                              hipStream_t stream) {
    const int*   nodes     = (const int*)d_in[0];
    const int*   neigh_idx = (const int*)d_in[1];
    const float* features  = (const float*)d_in[2];
    const float* W_stc     = (const float*)d_in[3];
    const float* W_det     = (const float*)d_in[4];
    float* out = (float*)d_out;

    const size_t P_BYTES   = (size_t)REL * N_NODES * HID * 2;   // 51,200,000
    const size_t BD_BYTES  = 512 * 128 * 2;                     // 131,072
    const size_t BS_BYTES  = 256 * 256 * 2;                     // 131,072
    const size_t WS_NEEDED = P_BYTES + BD_BYTES + BS_BYTES;

    if (ws_size >= WS_NEEDED) {
        unsigned short* P       = (unsigned short*)d_ws;
        unsigned short* Bsw_det = (unsigned short*)((char*)d_ws + P_BYTES);
        unsigned short* Bsw_stc = (unsigned short*)((char*)d_ws + P_BYTES + BD_BYTES);
        prep_Bf16<<<128, 256, 0, stream>>>(W_stc, W_det, Bsw_det, Bsw_stc);
        prep_P4<<<(N_NODES + 63) / 64, 512, 0, stream>>>(features, Bsw_stc, P);
        fused2<<<BATCH / 16, 256, 0, stream>>>(nodes, neigh_idx, features, P, Bsw_det, out);
    } else {
        unsigned short* Bsw = (unsigned short*)d_ws;            // 192 KB
        prep_B_old<<<272, 256, 0, stream>>>(W_stc, W_det, Bsw);
        fused_old<<<BATCH / 16, 256, 0, stream>>>(nodes, neigh_idx, features, Bsw, out);
    }
}

// Round 10
// 204.262 us; speedup vs baseline: 1.2195x; 1.0592x over previous
//
#include <hip/hip_runtime.h>
#include <hip/hip_bf16.h>

// Problem constants (from reference)
#define N_NODES 100000
#define FEAT    256
#define HID     128
#define REL     2
#define BATCH   20000
#define KNEI    10

#define APAD    8            // pad shorts per LDS A row (breaks pow-2 stride)
#define AROW    (768 + APAD) // 776 shorts = 1552 B row stride

typedef short  bf16x8 __attribute__((ext_vector_type(8)));
typedef float  f32x4  __attribute__((ext_vector_type(4)));
typedef unsigned u32x2 __attribute__((ext_vector_type(2)));

// ---------------- helpers ----------------
__device__ __forceinline__ unsigned short f2bf(float x) {
    union { float f; unsigned u; } v; v.f = x;
    unsigned r = v.u + 0x7fffu + ((v.u >> 16) & 1u);   // RNE
    return (unsigned short)(r >> 16);
}
__device__ __forceinline__ ushort4 pack4(float a, float b, float c, float d) {
    ushort4 p; p.x = f2bf(a); p.y = f2bf(b); p.z = f2bf(c); p.w = f2bf(d);
    return p;
}
__device__ __forceinline__ unsigned short f2h(float x) {
    union { _Float16 h; unsigned short u; } t; t.h = (_Float16)x; return t.u;
}
__device__ __forceinline__ ushort4 pack4h(float a, float b, float c, float d) {
    ushort4 p; p.x = f2h(a); p.y = f2h(b); p.z = f2h(c); p.w = f2h(d); return p;
}
// accumulate 4 packed halves into 4 fp32 sums
__device__ __forceinline__ void h4acc(u32x2 r, float4& s) {
    union { unsigned u; _Float16 h[2]; } t;
    t.u = r.x; s.x += (float)t.h[0]; s.y += (float)t.h[1];
    t.u = r.y; s.z += (float)t.h[0]; s.w += (float)t.h[1];
}

// Swizzled B index for logical (k, n) (8 n-tiles):
//   kt=k>>5, j=k&7, hi=(k>>3)&3, lane=hi*16+(n&15), nt=n>>4
__device__ __forceinline__ size_t bsw_index(int k, int n) {
    int kt = k >> 5, j = k & 7, hi = (k >> 3) & 3;
    int lane = hi * 16 + (n & 15), nt = n >> 4;
    return ((size_t)(kt * 8 + nt) * 64 + lane) * 8 + j;
}

// ---------------------------------------------------------------------------
// conv_h: plain grid-stride fp32 -> fp16 stream of the feature table.
// No phases, no barriers — the m13-style float4 copy pattern (6.3 TB/s).
// ---------------------------------------------------------------------------
__global__ __launch_bounds__(256) void conv_h(const float* __restrict__ features,
                                              unsigned short* __restrict__ Fh) {
    const int stride = gridDim.x * blockDim.x;
    const int n4 = N_NODES * FEAT / 4;               // 6,400,000 float4 groups
    const float4* src = (const float4*)features;
    ushort4* dst = (ushort4*)Fh;
    for (int i = blockIdx.x * blockDim.x + threadIdx.x; i < n4; i += stride) {
        float4 v = src[i];
        dst[i] = pack4h(v.x, v.y, v.z, v.w);
    }
}

// ---------------------------------------------------------------------------
// prep_B: collapsed weight into MFMA-swizzled bf16 (round-4 verbatim).
// ---------------------------------------------------------------------------
__global__ __launch_bounds__(256) void prep_B(const float* __restrict__ W_stc,
                                              const float* __restrict__ W_det,
                                              unsigned short* __restrict__ Bsw) {
    const int blk = blockIdx.x;
    const int tid = threadIdx.x;
    if (blk < 256) {
        const int rel = blk >> 7;
        const int f   = (blk & 127) * 2 + (tid >> 7);
        const int n   = tid & 127;
        const float* ws = W_stc + (size_t)(rel * FEAT + f) * HID;
        const float* wd = W_det + (size_t)(256 + rel * HID) * HID + n;
        float acc = 0.f;
        #pragma unroll
        for (int j = 0; j < HID; ++j) acc += ws[j] * wd[(size_t)j * HID];
        Bsw[bsw_index(256 + rel * 256 + f, n)] = f2bf(acc);
    } else {
        const int base = (blk - 256) * 2048;
        #pragma unroll
        for (int i = 0; i < 8; ++i) {
            const int idx = base + i * 256 + tid;
            const int k = idx >> 7, n = idx & 127;
            Bsw[bsw_index(k, n)] = f2bf(W_det[idx]);
        }
    }
}

// ---------------------------------------------------------------------------
// fused_h: round-4 fused with the gather retargeted at the fp16 table.
//   Per element: 21 rows x 512 B (8 B/lane dwordx2, forced-MLP inline asm,
//   same vmcnt(10)/vmcnt(0) schedule). 50 MB table is L3-resident ->
//   HBM fetch for the gather ~ 0; logical bytes halved (420 -> 210 MB).
//   Phase 2 (bf16 MFMA vs collapsed Bsw) unchanged from round 4.
// ---------------------------------------------------------------------------
__global__ __launch_bounds__(256, 4) void fused_h(const int* __restrict__ nodes,
                                                  const int* __restrict__ neigh_idx,
                                                  const unsigned short* __restrict__ Fh,
                                                  const unsigned short* __restrict__ Bsw,
                                                  float* __restrict__ out) {
    __shared__ unsigned short As[16 * AROW];   // 24832 B
    __shared__ int idxs[336];

    const int blk  = blockIdx.x;
    const int tid  = threadIdx.x;
    const int w    = tid >> 6;
    const int lane = tid & 63;
    const float inv = 1.0f / (float)KNEI;

    // ---- Phase 0: stage indices into LDS (coalesced) ----
    if (tid < 16)       idxs[tid] = nodes[blk * 16 + tid];
    else if (tid < 176) idxs[tid] = neigh_idx[blk * 160 + (tid - 16)];
    else                idxs[tid] = neigh_idx[BATCH * KNEI + blk * 160 + (tid - 176)];
    const int t2 = tid + 256;
    if (t2 < 336)       idxs[t2] = neigh_idx[BATCH * KNEI + blk * 160 + (t2 - 176)];
    __syncthreads();

    // ---- Phase 1: fp16 gather + mean (8 B/lane rows) ----
    const unsigned lnoff = (unsigned)lane << 3;          // lane byte offset in 512-B row
    #pragma unroll
    for (int e = 0; e < 4; ++e) {
        const int m = w * 4 + e;
        int ia[11], ib[10];
        ia[0] = idxs[m];
        #pragma unroll
        for (int k = 0; k < KNEI; ++k) ia[1 + k] = idxs[16 + m * KNEI + k];
        #pragma unroll
        for (int k = 0; k < KNEI; ++k) ib[k]     = idxs[176 + m * KNEI + k];

        u32x2 ta[11];                          // self + rel0 (4 halves each)
        #pragma unroll
        for (int k = 0; k < 11; ++k) {
            const unsigned voff = ((unsigned)ia[k] << 9) + lnoff;   // idx*512 + lane*8
            asm volatile("global_load_dwordx2 %0, %1, %2"
                         : "=v"(ta[k]) : "v"(voff), "s"(Fh));
        }
        u32x2 tb[10];                          // rel1
        #pragma unroll
        for (int k = 0; k < KNEI; ++k) {
            const unsigned voff = ((unsigned)ib[k] << 9) + lnoff;
            asm volatile("global_load_dwordx2 %0, %1, %2"
                         : "=v"(tb[k]) : "v"(voff), "s"(Fh));
        }

        asm volatile("s_waitcnt vmcnt(10)" ::: "memory");
        __builtin_amdgcn_sched_barrier(0);

        float4 sf = make_float4(0.f, 0.f, 0.f, 0.f);
        h4acc(ta[0], sf);
        float4 s0 = make_float4(0.f, 0.f, 0.f, 0.f);
        #pragma unroll
        for (int k = 1; k < 11; ++k) h4acc(ta[k], s0);

        ushort4* row = (ushort4*)(As + m * AROW);
        row[lane]      = pack4(sf.x, sf.y, sf.z, sf.w);
        row[64 + lane] = pack4(s0.x * inv, s0.y * inv, s0.z * inv, s0.w * inv);

        asm volatile("s_waitcnt vmcnt(0)" ::: "memory");
        __builtin_amdgcn_sched_barrier(0);

        float4 s1 = make_float4(0.f, 0.f, 0.f, 0.f);
        #pragma unroll
        for (int k = 0; k < KNEI; ++k) h4acc(tb[k], s1);
        row[128 + lane] = pack4(s1.x * inv, s1.y * inv, s1.z * inv, s1.w * inv);
    }
    __syncthreads();

    // ---- Phase 2: GEMM + ReLU (round-4 verbatim) ----
    const int quad = lane >> 4;
    const int l16  = lane & 15;
    const unsigned short* a_base = As + l16 * AROW + quad * 8;

    f32x4 acc0 = (f32x4){0.f, 0.f, 0.f, 0.f};
    f32x4 acc1 = (f32x4){0.f, 0.f, 0.f, 0.f};
    const int nt0 = w, nt1 = w + 4;

    #pragma unroll
    for (int kt = 0; kt < 24; ++kt) {
        bf16x8 a = *(const bf16x8*)(a_base + kt * 32);
        const unsigned short* bk = Bsw + ((size_t)(kt * 8) * 64 + lane) * 8;
        bf16x8 b0 = *(const bf16x8*)(bk + (size_t)nt0 * 64 * 8);
        bf16x8 b1 = *(const bf16x8*)(bk + (size_t)nt1 * 64 * 8);
        acc0 = __builtin_amdgcn_mfma_f32_16x16x32_bf16(a, b0, acc0, 0, 0, 0);
        acc1 = __builtin_amdgcn_mfma_f32_16x16x32_bf16(a, b1, acc1, 0, 0, 0);
    }

    float* orow = out + (size_t)(blk * 16) * HID;
    #pragma unroll
    for (int r = 0; r < 4; ++r) {
        const int row = quad * 4 + r;
        float v0 = acc0[r];
        float v1 = acc1[r];
        orow[(size_t)row * HID + nt0 * 16 + l16] = v0 > 0.f ? v0 : 0.f;
        orow[(size_t)row * HID + nt1 * 16 + l16] = v1 > 0.f ? v1 : 0.f;
    }
}

// ---------------------------------------------------------------------------
// Fallback (round-4 verbatim, fp32 gather): needs only 192 KB workspace.
// ---------------------------------------------------------------------------
__global__ __launch_bounds__(256, 4) void fused_old(const int* __restrict__ nodes,
                                                    const int* __restrict__ neigh_idx,
                                                    const float* __restrict__ features,
                                                    const unsigned short* __restrict__ Bsw,
                                                    float* __restrict__ out) {
    __shared__ unsigned short As[16 * AROW];
    __shared__ int idxs[336];

    const int blk  = blockIdx.x;
    const int tid  = threadIdx.x;
    const int w    = tid >> 6;
    const int lane = tid & 63;
    const float inv = 1.0f / (float)KNEI;

    if (tid < 16)       idxs[tid] = nodes[blk * 16 + tid];
    else if (tid < 176) idxs[tid] = neigh_idx[blk * 160 + (tid - 16)];
    else                idxs[tid] = neigh_idx[BATCH * KNEI + blk * 160 + (tid - 176)];
    const int t2 = tid + 256;
    if (t2 < 336)       idxs[t2] = neigh_idx[BATCH * KNEI + blk * 160 + (t2 - 176)];
    __syncthreads();

    const unsigned lnoff = (unsigned)lane << 4;
    #pragma unroll
    for (int e = 0; e < 4; ++e) {
        const int m = w * 4 + e;
        int ia[11], ib[10];
        ia[0] = idxs[m];
        #pragma unroll
        for (int k = 0; k < KNEI; ++k) ia[1 + k] = idxs[16 + m * KNEI + k];
        #pragma unroll
        for (int k = 0; k < KNEI; ++k) ib[k]     = idxs[176 + m * KNEI + k];

        f32x4 ta[11];
        #pragma unroll
        for (int k = 0; k < 11; ++k) {
            const unsigned voff = ((unsigned)ia[k] << 10) + lnoff;
            asm volatile("global_load_dwordx4 %0, %1, %2"
                         : "=v"(ta[k]) : "v"(voff), "s"(features));
        }
        f32x4 tb[10];
        #pragma unroll
        for (int k = 0; k < KNEI; ++k) {
            const unsigned voff = ((unsigned)ib[k] << 10) + lnoff;
            asm volatile("global_load_dwordx4 %0, %1, %2"
                         : "=v"(tb[k]) : "v"(voff), "s"(features));
        }

        asm volatile("s_waitcnt vmcnt(10)" ::: "memory");
        __builtin_amdgcn_sched_barrier(0);

        f32x4 s0 = ta[1];
        #pragma unroll
        for (int k = 2; k < 11; ++k) s0 += ta[k];

        ushort4* row = (ushort4*)(As + m * AROW);
        row[lane]      = pack4(ta[0][0], ta[0][1], ta[0][2], ta[0][3]);
        row[64 + lane] = pack4(s0[0] * inv, s0[1] * inv, s0[2] * inv, s0[3] * inv);

        asm volatile("s_waitcnt vmcnt(0)" ::: "memory");
        __builtin_amdgcn_sched_barrier(0);

        f32x4 s1 = tb[0];
        #pragma unroll
        for (int k = 1; k < KNEI; ++k) s1 += tb[k];
        row[128 + lane] = pack4(s1[0] * inv, s1[1] * inv, s1[2] * inv, s1[3] * inv);
    }
    __syncthreads();

    const int quad = lane >> 4;
    const int l16  = lane & 15;
    const unsigned short* a_base = As + l16 * AROW + quad * 8;

    f32x4 acc0 = (f32x4){0.f, 0.f, 0.f, 0.f};
    f32x4 acc1 = (f32x4){0.f, 0.f, 0.f, 0.f};
    const int nt0 = w, nt1 = w + 4;

    #pragma unroll
    for (int kt = 0; kt < 24; ++kt) {
        bf16x8 a = *(const bf16x8*)(a_base + kt * 32);
        const unsigned short* bk = Bsw + ((size_t)(kt * 8) * 64 + lane) * 8;
        bf16x8 b0 = *(const bf16x8*)(bk + (size_t)nt0 * 64 * 8);
        bf16x8 b1 = *(const bf16x8*)(bk + (size_t)nt1 * 64 * 8);
        acc0 = __builtin_amdgcn_mfma_f32_16x16x32_bf16(a, b0, acc0, 0, 0, 0);
        acc1 = __builtin_amdgcn_mfma_f32_16x16x32_bf16(a, b1, acc1, 0, 0, 0);
    }

    float* orow = out + (size_t)(blk * 16) * HID;
    #pragma unroll
    for (int r = 0; r < 4; ++r) {
        const int row = quad * 4 + r;
        float v0 = acc0[r];
        float v1 = acc1[r];
        orow[(size_t)row * HID + nt0 * 16 + l16] = v0 > 0.f ? v0 : 0.f;
        orow[(size_t)row * HID + nt1 * 16 + l16] = v1 > 0.f ? v1 : 0.f;
    }
}

// ===========================================================================
extern "C" void kernel_launch(void* const* d_in, const int* in_sizes, int n_in,
                              void* d_out, int out_size, void* d_ws, size_t ws_size,
                              hipStream_t stream) {
    const int*   nodes     = (const int*)d_in[0];
    const int*   neigh_idx = (const int*)d_in[1];
    const float* features  = (const float*)d_in[2];
    const float* W_stc     = (const float*)d_in[3];
    const float* W_det     = (const float*)d_in[4];
    float* out = (float*)d_out;

    const size_t FH_BYTES  = (size_t)N_NODES * FEAT * 2;   // 51,200,000
    const size_t BSW_BYTES = 768 * 128 * 2;                // 196,608
    const size_t WS_NEEDED = FH_BYTES + BSW_BYTES;

    if (ws_size >= WS_NEEDED) {
        unsigned short* Fh  = (unsigned short*)d_ws;
        unsigned short* Bsw = (unsigned short*)((char*)d_ws + FH_BYTES);
        conv_h<<<2048, 256, 0, stream>>>(features, Fh);
        prep_B<<<272, 256, 0, stream>>>(W_stc, W_det, Bsw);
        fused_h<<<BATCH / 16, 256, 0, stream>>>(nodes, neigh_idx, Fh, Bsw, out);
    } else {
        unsigned short* Bsw = (unsigned short*)d_ws;       // 192 KB
        prep_B<<<272, 256, 0, stream>>>(W_stc, W_det, Bsw);
        fused_old<<<BATCH / 16, 256, 0, stream>>>(nodes, neigh_idx, features, Bsw, out);
    }
}